// Round 13
// baseline (78.893 us; speedup 1.0000x reference)
//
#include <hip/hip_runtime.h>
#include <hip/hip_fp16.h>
#include <math.h>

#define RES 256
#define TPAD 364              // padded texture dim: image coords -53..310
#define N_ANGLES 256
#define NAQ 65                // quad angle slots: {a, 256-a, 128-a, 128+a}
#define BATCH 8
#define CELLB 64              // cell bytes: 4 planes x 16B (8 x fp16 each)
#define ROWB (TPAD * CELLB)   // row pitch bytes (23296)

typedef _Float16 h2 __attribute__((ext_vector_type(2)));
__device__ inline h2 u2h(unsigned u) { return __builtin_bit_cast(h2, u); }

// Cell-packed texture: T[r][c] = 64B = 4 planes x (8 x fp16), zero outside:
//  p0: img(r,c)  p1: img(r,255-c)  p2: img(c,r)  p3: img(c,255-r)
// One 64B line = EVERYTHING needed for one bilinear tap of 4 angles x 8 batches.
__global__ void prep_pack(const float* __restrict__ imgs,
                          unsigned int* __restrict__ W) {
    int idx = blockIdx.x * blockDim.x + threadIdx.x;
    const int total = 4 * TPAD * TPAD * 4;      // plane x pixel x batch-pair
    if (idx >= total) return;
    int pair  = idx & 3;
    int px    = (idx >> 2) % (TPAD * TPAD);
    int plane = (idx >> 2) / (TPAD * TPAD);
    int orient = plane >> 1, side = plane & 1;
    int ct = px % TPAD, rt = px / TPAD;
    int ri = rt - 53, ci = ct - 53;
    int row, col;
    if (orient == 0) { row = ri; col = side ? (255 - ci) : ci; }
    else             { row = ci; col = side ? (255 - ri) : ri; }
    float v0 = 0.0f, v1 = 0.0f;
    if ((unsigned)row < RES && (unsigned)col < RES) {
        const float* p = imgs + ((size_t)(pair * 2) * RES + row) * RES + col;
        v0 = p[0];
        v1 = p[RES * RES];
    }
    __half2 h = __halves2half2(__float2half_rn(v0), __float2half_rn(v1));
    W[(size_t)px * 16 + plane * 4 + pair] = *reinterpret_cast<unsigned int*>(&h);
}

// Direct gather, square wave footprint, cell-packed lines.
// Lane = tap(2b) | tl(2b) | sl(2b) | wave(2b). Block = (quad-angle a, 4 s).
// Per lane-step: ONE coord+weight computation, 4 loads at imm offsets 0/16/32/48
// of ONE 64B line -> 4 angles x 8 batches. All t in-block -> direct f32 output.
__global__ __launch_bounds__(256) void radon_kernel(
        const char* __restrict__ TEX,
        const float* __restrict__ angles,
        float* __restrict__ out) {
    __shared__ float scrf[4][4][32];

    const int tid = threadIdx.x;
    const int tap = tid & 3;
    const int tl  = (tid >> 2) & 3;
    const int sl  = (tid >> 4) & 3;
    const int wid = tid >> 6;
    const int a   = blockIdx.x;            // 0..64, theta in [0, pi/4]
    const int s0  = blockIdx.y * 4;

    float theta = angles[a];
    float sn, cs;
    sincosf(theta, &sn, &cs);
    const float Rs = sn, Rt = cs, Cs = cs, Ct = -sn;   // Rt >= 0.7071

    const float s_c = (float)(s0 + sl) - 127.5f;
    const float prA = fmaf(s_c, Rs, 180.5f);
    const float pcA = fmaf(s_c, Cs, 180.5f);
    const float pr0 = prA - 127.5f * Rt;
    const float pc0 = pcA - 127.5f * Ct;

    // work clip: nonzero bilinear only for padded coords in [52, 309]
    const float LO = 52.0f, HI = 309.0f;
    float tmin = 0.0f, tmax = 255.0f;
    {
        float inv = 1.0f / Rt;
        float ta = (LO - pr0) * inv, tb = (HI - pr0) * inv;
        tmin = fmaxf(tmin, fminf(ta, tb));
        tmax = fminf(tmax, fmaxf(ta, tb));
    }
    if (fabsf(Ct) > 1e-6f) {
        float inv = 1.0f / Ct;
        float ta = (LO - pc0) * inv, tb = (HI - pc0) * inv;
        tmin = fmaxf(tmin, fminf(ta, tb));
        tmax = fminf(tmax, fmaxf(ta, tb));
    } else if (!(pc0 >= LO && pc0 <= HI)) {
        tmax = -1.0f;
    }

    const int tt = wid * 4 + tl;          // 0..15; lane t = tt + 16k
    int kmin = (int)ceilf((tmin - (float)tt) * 0.0625f);
    int kmax = (int)floorf((tmax - (float)tt) * 0.0625f);
    kmin = max(kmin, 0);
    kmax = min(kmax, 15);

    const int dr = tap >> 1, dc = tap & 1;
    const unsigned tapoff = (unsigned)(dr * ROWB + dc * CELLB);
    const float xb = dc ? 0.0f : 1.0f, xs = dc ? 1.0f : -1.0f;
    const float yb = dr ? 0.0f : 1.0f, ys = dr ? 1.0f : -1.0f;

    h2 acc[16];
    #pragma unroll
    for (int i = 0; i < 16; ++i) acc[i] = h2{};

    float tf = (float)(tt + 16 * kmin) - 127.5f;
    for (int k = kmin; k <= kmax; ++k) {
        float ppr = fmaf(tf, Rt, prA);
        float ppc = fmaf(tf, Ct, pcA);
        tf += 16.0f;
        float wy, wx;
        int ir, ic;
        asm("v_fract_f32 %0, %1"       : "=v"(wy) : "v"(ppr));
        asm("v_fract_f32 %0, %1"       : "=v"(wx) : "v"(ppc));
        asm("v_cvt_flr_i32_f32 %0, %1" : "=v"(ir) : "v"(ppr));
        asm("v_cvt_flr_i32_f32 %0, %1" : "=v"(ic) : "v"(ppc));
        unsigned x = ((unsigned)ic << 6) + tapoff;     // v_lshl_add_u32
        unsigned bo;
        asm("v_mad_u32_u24 %0, %1, %2, %3"
            : "=v"(bo) : "v"(ir), "s"(ROWB), "v"(x));
        float w = fmaf(xs, wx, xb) * fmaf(ys, wy, yb);
        auto pkr = __builtin_amdgcn_cvt_pkrtz(w, w);
        h2 wv = __builtin_bit_cast(h2, pkr);

        // One 64B line: 4 planes at imm offsets 0/16/32/48.
        uint4 q0 = *(const uint4*)(TEX + bo);
        uint4 q1 = *(const uint4*)(TEX + bo + 16);
        uint4 q2 = *(const uint4*)(TEX + bo + 32);
        uint4 q3 = *(const uint4*)(TEX + bo + 48);

        acc[0]  = wv * u2h(q0.x) + acc[0];   acc[1]  = wv * u2h(q0.y) + acc[1];
        acc[2]  = wv * u2h(q0.z) + acc[2];   acc[3]  = wv * u2h(q0.w) + acc[3];
        acc[4]  = wv * u2h(q1.x) + acc[4];   acc[5]  = wv * u2h(q1.y) + acc[5];
        acc[6]  = wv * u2h(q1.z) + acc[6];   acc[7]  = wv * u2h(q1.w) + acc[7];
        acc[8]  = wv * u2h(q2.x) + acc[8];   acc[9]  = wv * u2h(q2.y) + acc[9];
        acc[10] = wv * u2h(q2.z) + acc[10];  acc[11] = wv * u2h(q2.w) + acc[11];
        acc[12] = wv * u2h(q3.x) + acc[12];  acc[13] = wv * u2h(q3.y) + acc[13];
        acc[14] = wv * u2h(q3.z) + acc[14];  acc[15] = wv * u2h(q3.w) + acc[15];
    }

    // reduce taps (bits 0-1) and tl (bits 2-3) in f32
    float rx[16], ry[16];
    #pragma unroll
    for (int i = 0; i < 16; ++i) { rx[i] = (float)acc[i].x; ry[i] = (float)acc[i].y; }
    #pragma unroll
    for (int i = 0; i < 16; ++i) {
        rx[i] += __shfl_xor(rx[i], 1);  ry[i] += __shfl_xor(ry[i], 1);
        rx[i] += __shfl_xor(rx[i], 2);  ry[i] += __shfl_xor(ry[i], 2);
        rx[i] += __shfl_xor(rx[i], 4);  ry[i] += __shfl_xor(ry[i], 4);
        rx[i] += __shfl_xor(rx[i], 8);  ry[i] += __shfl_xor(ry[i], 8);
    }
    if ((tid & 15) == 0) {
        #pragma unroll
        for (int i = 0; i < 16; ++i) {
            scrf[wid][sl][2 * i]     = rx[i];
            scrf[wid][sl][2 * i + 1] = ry[i];
        }
    }
    __syncthreads();

    if (tid < 128) {
        int s_idx = tid >> 5, o = tid & 31;     // o = p*8 + b
        int p = o >> 3, b = o & 7;
        int word = (p * 4 + (b >> 1)) * 2 + (b & 1);
        float sum = scrf[0][s_idx][word] + scrf[1][s_idx][word]
                  + scrf[2][s_idx][word] + scrf[3][s_idx][word];
        int ai;
        bool wr = true;
        if      (p == 0) { ai = a; }
        else if (p == 1) { ai = 256 - a; wr = (a != 0); }
        else if (p == 2) { ai = 128 - a; wr = (a != 64); }
        else             { ai = 128 + a; wr = (a != 0) && (a != 64); }
        if (wr)
            out[((size_t)b * N_ANGLES + ai) * RES + (s0 + s_idx)] = sum;
    }
}

extern "C" void kernel_launch(void* const* d_in, const int* in_sizes, int n_in,
                              void* d_out, int out_size, void* d_ws, size_t ws_size,
                              hipStream_t stream) {
    const float* imgs   = (const float*)d_in[0];
    const float* angles = (const float*)d_in[1];
    float* out = (float*)d_out;

    char* TEX = (char*)d_ws;                                 // 8.48 MB cells

    const int prep_total = 4 * TPAD * TPAD * 4;
    prep_pack<<<(prep_total + 255) / 256, 256, 0, stream>>>(
        imgs, (unsigned int*)TEX);

    dim3 grid(NAQ, RES / 4);                                 // 65 x 64 blocks
    radon_kernel<<<grid, 256, 0, stream>>>(TEX, angles, out);
}

// Round 14
// 57.986 us; speedup vs baseline: 1.3605x; 1.3605x over previous
//
#include <hip/hip_runtime.h>
#include <hip/hip_fp16.h>
#include <math.h>

#define RES 256
#define TPAD 364              // padded texture dim: image coords -53..310
#define N_ANGLES 256
#define NAQ 65                // quad angle slots: {a, 256-a, 128-a, 128+a}
#define BATCH 8
#define ROWB (TPAD * 16)      // plane row pitch bytes (5824)

typedef _Float16 h2 __attribute__((ext_vector_type(2)));
__device__ inline h2 u2h(unsigned u) { return __builtin_bit_cast(h2, u); }

// Four planes of 16B texels (8 x fp16), each TPAD x TPAD, zero outside image:
//  p0: img(r,c)  p1: img(r,255-c)  p2: img(c,r)  p3: img(c,255-r)
// Serves angles {a, 256-a, 128-a, 128+a} from ONE coordinate computation.
__global__ void prep_pack(const float* __restrict__ imgs,
                          unsigned int* __restrict__ W) {
    int idx = blockIdx.x * blockDim.x + threadIdx.x;
    const int total = 4 * TPAD * TPAD * 4;
    if (idx >= total) return;
    int pair  = idx & 3;
    int px    = (idx >> 2) % (TPAD * TPAD);
    int plane = (idx >> 2) / (TPAD * TPAD);
    int orient = plane >> 1, side = plane & 1;
    int ct = px % TPAD, rt = px / TPAD;
    int ri = rt - 53, ci = ct - 53;
    int row, col;
    if (orient == 0) { row = ri; col = side ? (255 - ci) : ci; }
    else             { row = ci; col = side ? (255 - ri) : ri; }
    float v0 = 0.0f, v1 = 0.0f;
    if ((unsigned)row < RES && (unsigned)col < RES) {
        const float* p = imgs + ((size_t)(pair * 2) * RES + row) * RES + col;
        v0 = p[0];
        v1 = p[RES * RES];
    }
    __half2 h = __halves2half2(__float2half_rn(v0), __float2half_rn(v1));
    W[((size_t)plane * TPAD * TPAD + px) * 4 + pair] =
        *reinterpret_cast<unsigned int*>(&h);
}

// Direct-gather, square wave footprint. Lane = tap(2b) | tl(2b) | sl(2b) | wave(2b).
// Block = (quad-angle a, 4 s); waves cover t = (4*wid + tl) + 16k, k=0..15.
// Per lane-step: ONE coord+weight computation, FOUR plane loads from one boff
// -> 4 angles x 8 batches. All t in-block -> direct f32 output, no partials.
__global__ __launch_bounds__(256) void radon_kernel(
        const char* __restrict__ TEX,
        const float* __restrict__ angles,
        float* __restrict__ out) {
    __shared__ float scrf[4][4][32];

    const int tid = threadIdx.x;
    const int tap = tid & 3;
    const int tl  = (tid >> 2) & 3;
    const int sl  = (tid >> 4) & 3;
    const int wid = tid >> 6;
    const int a   = blockIdx.x;            // 0..64, theta in [0, pi/4]
    const int s0  = blockIdx.y * 4;

    float theta = angles[a];
    float sn, cs;
    sincosf(theta, &sn, &cs);
    const float Rs = sn, Rt = cs, Cs = cs, Ct = -sn;   // Rt >= 0.7071

    const float s_c = (float)(s0 + sl) - 127.5f;
    const float prA = fmaf(s_c, Rs, 180.5f);
    const float pcA = fmaf(s_c, Cs, 180.5f);
    const float pr0 = prA - 127.5f * Rt;
    const float pc0 = pcA - 127.5f * Ct;

    // work clip: nonzero bilinear only for padded coords in [52, 309]
    const float LO = 52.0f, HI = 309.0f;
    float tmin = 0.0f, tmax = 255.0f;
    {
        float inv = 1.0f / Rt;
        float ta = (LO - pr0) * inv, tb = (HI - pr0) * inv;
        tmin = fmaxf(tmin, fminf(ta, tb));
        tmax = fminf(tmax, fmaxf(ta, tb));
    }
    if (fabsf(Ct) > 1e-6f) {
        float inv = 1.0f / Ct;
        float ta = (LO - pc0) * inv, tb = (HI - pc0) * inv;
        tmin = fmaxf(tmin, fminf(ta, tb));
        tmax = fminf(tmax, fmaxf(ta, tb));
    } else if (!(pc0 >= LO && pc0 <= HI)) {
        tmax = -1.0f;
    }

    const int tt = wid * 4 + tl;          // 0..15; lane t = tt + 16k
    int kmin = (int)ceilf((tmin - (float)tt) * 0.0625f);
    int kmax = (int)floorf((tmax - (float)tt) * 0.0625f);
    kmin = max(kmin, 0);
    kmax = min(kmax, 15);

    const int dr = tap >> 1, dc = tap & 1;
    const unsigned tapoff = (unsigned)(dr * ROWB + dc * 16);
    const float xb = dc ? 0.0f : 1.0f, xs = dc ? 1.0f : -1.0f;
    const float yb = dr ? 0.0f : 1.0f, ys = dr ? 1.0f : -1.0f;

    const size_t planeGB = (size_t)TPAD * TPAD * 16;
    const char* b0 = TEX;
    const char* b1 = TEX + planeGB;
    const char* b2 = TEX + 2 * planeGB;
    const char* b3 = TEX + 3 * planeGB;

    h2 acc[16];
    #pragma unroll
    for (int i = 0; i < 16; ++i) acc[i] = h2{};

    float tf = (float)(tt + 16 * kmin) - 127.5f;
    for (int k = kmin; k <= kmax; ++k) {
        float ppr = fmaf(tf, Rt, prA);
        float ppc = fmaf(tf, Ct, pcA);
        tf += 16.0f;
        float wy, wx;
        int ir, ic;
        asm("v_fract_f32 %0, %1"       : "=v"(wy) : "v"(ppr));
        asm("v_fract_f32 %0, %1"       : "=v"(wx) : "v"(ppc));
        asm("v_cvt_flr_i32_f32 %0, %1" : "=v"(ir) : "v"(ppr));
        asm("v_cvt_flr_i32_f32 %0, %1" : "=v"(ic) : "v"(ppc));
        unsigned x = ((unsigned)ic << 4) + tapoff;
        unsigned bo;
        asm("v_mad_u32_u24 %0, %1, %2, %3"
            : "=v"(bo) : "v"(ir), "s"(ROWB), "v"(x));
        float w = fmaf(xs, wx, xb) * fmaf(ys, wy, yb);
        auto pkr = __builtin_amdgcn_cvt_pkrtz(w, w);
        h2 wv = __builtin_bit_cast(h2, pkr);

        uint4 q0 = *(const uint4*)(b0 + bo);
        uint4 q1 = *(const uint4*)(b1 + bo);
        uint4 q2 = *(const uint4*)(b2 + bo);
        uint4 q3 = *(const uint4*)(b3 + bo);

        acc[0]  = wv * u2h(q0.x) + acc[0];   acc[1]  = wv * u2h(q0.y) + acc[1];
        acc[2]  = wv * u2h(q0.z) + acc[2];   acc[3]  = wv * u2h(q0.w) + acc[3];
        acc[4]  = wv * u2h(q1.x) + acc[4];   acc[5]  = wv * u2h(q1.y) + acc[5];
        acc[6]  = wv * u2h(q1.z) + acc[6];   acc[7]  = wv * u2h(q1.w) + acc[7];
        acc[8]  = wv * u2h(q2.x) + acc[8];   acc[9]  = wv * u2h(q2.y) + acc[9];
        acc[10] = wv * u2h(q2.z) + acc[10];  acc[11] = wv * u2h(q2.w) + acc[11];
        acc[12] = wv * u2h(q3.x) + acc[12];  acc[13] = wv * u2h(q3.y) + acc[13];
        acc[14] = wv * u2h(q3.z) + acc[14];  acc[15] = wv * u2h(q3.w) + acc[15];
    }

    // reduce taps (bits 0-1) and tl (bits 2-3) in f32
    float rx[16], ry[16];
    #pragma unroll
    for (int i = 0; i < 16; ++i) { rx[i] = (float)acc[i].x; ry[i] = (float)acc[i].y; }
    #pragma unroll
    for (int i = 0; i < 16; ++i) {
        rx[i] += __shfl_xor(rx[i], 1);  ry[i] += __shfl_xor(ry[i], 1);
        rx[i] += __shfl_xor(rx[i], 2);  ry[i] += __shfl_xor(ry[i], 2);
        rx[i] += __shfl_xor(rx[i], 4);  ry[i] += __shfl_xor(ry[i], 4);
        rx[i] += __shfl_xor(rx[i], 8);  ry[i] += __shfl_xor(ry[i], 8);
    }
    if ((tid & 15) == 0) {
        #pragma unroll
        for (int i = 0; i < 16; ++i) {
            scrf[wid][sl][2 * i]     = rx[i];
            scrf[wid][sl][2 * i + 1] = ry[i];
        }
    }
    __syncthreads();

    if (tid < 128) {
        int s_idx = tid >> 5, o = tid & 31;     // o = p*8 + b
        int p = o >> 3, b = o & 7;
        int word = (p * 4 + (b >> 1)) * 2 + (b & 1);
        float sum = scrf[0][s_idx][word] + scrf[1][s_idx][word]
                  + scrf[2][s_idx][word] + scrf[3][s_idx][word];
        int ai;
        bool wr = true;
        if      (p == 0) { ai = a; }
        else if (p == 1) { ai = 256 - a; wr = (a != 0); }
        else if (p == 2) { ai = 128 - a; wr = (a != 64); }
        else             { ai = 128 + a; wr = (a != 0) && (a != 64); }
        if (wr)
            out[((size_t)b * N_ANGLES + ai) * RES + (s0 + s_idx)] = sum;
    }
}

extern "C" void kernel_launch(void* const* d_in, const int* in_sizes, int n_in,
                              void* d_out, int out_size, void* d_ws, size_t ws_size,
                              hipStream_t stream) {
    const float* imgs   = (const float*)d_in[0];
    const float* angles = (const float*)d_in[1];
    float* out = (float*)d_out;

    char* TEX = (char*)d_ws;                                 // 4 planes, 8.48 MB

    const int prep_total = 4 * TPAD * TPAD * 4;
    prep_pack<<<(prep_total + 255) / 256, 256, 0, stream>>>(
        imgs, (unsigned int*)TEX);

    dim3 grid(NAQ, RES / 4);                                 // 65 x 64 blocks
    radon_kernel<<<grid, 256, 0, stream>>>(TEX, angles, out);
}